// Round 1
// baseline (386.192 us; speedup 1.0000x reference)
//
#include <hip/hip_runtime.h>
#include <hip/hip_bf16.h>

// Sizes fixed by the problem
#define NB 8
#define NC 64
#define NA 32
#define NN 4096

typedef __attribute__((ext_vector_type(8))) short bf16x8;
typedef __attribute__((ext_vector_type(4))) float f32x4;

__device__ inline ushort f2bf(float f) {
  union { float f; unsigned u; } v; v.f = f;
  unsigned r = v.u + 0x7fffu + ((v.u >> 16) & 1u);
  return (ushort)(r >> 16);
}

// ---------------------------------------------------------------------------
// Kernel 1: g = Wg@x + bg, hq = Wh@x + bh  (per batch, 1x1 conv == GEMM)
// Writes bf16: gT[b][n][a], hqT[b][n][a]  (K=a contiguous for MFMA frags)
// and xfb[b][c][n] = bf16(x).
// One thread per (b, n). Weights staged in LDS (broadcast reads).
// ---------------------------------------------------------------------------
__global__ __launch_bounds__(256) void prep_kernel(
    const float* __restrict__ x, const float* __restrict__ Wg, const float* __restrict__ bg,
    const float* __restrict__ Wh, const float* __restrict__ bh,
    ushort* __restrict__ gT, ushort* __restrict__ hqT, ushort* __restrict__ xfb)
{
  __shared__ float wg_s[NA * NC];
  __shared__ float wh_s[NA * NC];
  const int t = threadIdx.x;
  for (int i = t; i < NA * NC; i += 256) { wg_s[i] = Wg[i]; wh_s[i] = Wh[i]; }
  __syncthreads();

  const int gid = blockIdx.x * 256 + t;
  const int b = gid >> 12;          // / NN
  const int n = gid & (NN - 1);
  const float* xb = x + (size_t)b * NC * NN + n;

  float accg[NA], acch[NA];
#pragma unroll
  for (int a = 0; a < NA; ++a) { accg[a] = 0.f; acch[a] = 0.f; }

  for (int c4 = 0; c4 < NC / 4; ++c4) {
    const float xv0 = xb[(size_t)(c4 * 4 + 0) * NN];
    const float xv1 = xb[(size_t)(c4 * 4 + 1) * NN];
    const float xv2 = xb[(size_t)(c4 * 4 + 2) * NN];
    const float xv3 = xb[(size_t)(c4 * 4 + 3) * NN];
    // bf16 copy of x (coalesced across threads)
    const size_t xo = ((size_t)b * NC + c4 * 4) * NN + n;
    xfb[xo]          = f2bf(xv0);
    xfb[xo + NN]     = f2bf(xv1);
    xfb[xo + 2 * NN] = f2bf(xv2);
    xfb[xo + 3 * NN] = f2bf(xv3);
#pragma unroll
    for (int a = 0; a < NA; ++a) {
      const float4 wg4 = *(const float4*)&wg_s[a * NC + c4 * 4];
      const float4 wh4 = *(const float4*)&wh_s[a * NC + c4 * 4];
      accg[a] += wg4.x * xv0 + wg4.y * xv1 + wg4.z * xv2 + wg4.w * xv3;
      acch[a] += wh4.x * xv0 + wh4.y * xv1 + wh4.z * xv2 + wh4.w * xv3;
    }
  }

  ushort og[NA], oh[NA];
#pragma unroll
  for (int a = 0; a < NA; ++a) {
    og[a] = f2bf(accg[a] + bg[a]);
    oh[a] = f2bf(acch[a] + bh[a]);
  }
  const size_t o = ((size_t)b * NN + n) * NA;   // 64B-aligned (32 shorts)
#pragma unroll
  for (int k = 0; k < 4; ++k) {
    uint4 vg, vh;
    vg.x = (uint)og[k*8+0] | ((uint)og[k*8+1] << 16);
    vg.y = (uint)og[k*8+2] | ((uint)og[k*8+3] << 16);
    vg.z = (uint)og[k*8+4] | ((uint)og[k*8+5] << 16);
    vg.w = (uint)og[k*8+6] | ((uint)og[k*8+7] << 16);
    vh.x = (uint)oh[k*8+0] | ((uint)oh[k*8+1] << 16);
    vh.y = (uint)oh[k*8+2] | ((uint)oh[k*8+3] << 16);
    vh.z = (uint)oh[k*8+4] | ((uint)oh[k*8+5] << 16);
    vh.w = (uint)oh[k*8+6] | ((uint)oh[k*8+7] << 16);
    *(uint4*)(gT  + o + k * 8) = vg;
    *(uint4*)(hqT + o + k * 8) = vh;
  }
}

// ---------------------------------------------------------------------------
// Kernel 2: fused scores -> softmax -> alpha write -> r = alpha @ x^T
// One wave (64 thr) per block; each wave owns 32 consecutive n-rows of one b.
// Pass A: sum of exp(s) per row (scores recomputed, K=A=32 -> 1 MFMA/tile).
// Pass B: p = exp(s)/L, write alpha, LDS-transpose p, r-GEMM via MFMA.
// MFMA 16x16x32 layouts: A: lane holds A[l&15][(l>>4)*8 + j];
//                        B: lane holds B[(l>>4)*8 + j][l&15];
//                        D: D[(l>>4)*4 + r][l&15]   (m89-verified)
// ---------------------------------------------------------------------------
__global__ __launch_bounds__(64) void attn_kernel(
    const ushort* __restrict__ gT, const ushort* __restrict__ hqT,
    const ushort* __restrict__ xfb, const float* __restrict__ x,
    float* __restrict__ outp, float* __restrict__ alpha)
{
  __shared__ ushort p_lds[2][32][40];   // pad 32->40 shorts: 16B-aligned rows, spreads banks
  const int l  = threadIdx.x;
  const int lm = l & 15;
  const int lh = l >> 4;
  const int blk = blockIdx.x;
  const int b  = blk >> 7;              // 128 blocks per batch
  const int n0 = (blk & 127) << 5;      // 32 rows per wave

  const ushort* gbase = gT  + (size_t)b * NN * NA;
  const ushort* hbase = hqT + (size_t)b * NN * NA;
  const ushort* xbase = xfb + (size_t)b * NC * NN;

  // g A-frags for the two 16-row groups (held in regs the whole kernel)
  bf16x8 ga[2];
#pragma unroll
  for (int gi = 0; gi < 2; ++gi)
    ga[gi] = *(const bf16x8*)(gbase + (size_t)(n0 + gi * 16 + lm) * NA + lh * 8);

  const f32x4 zz = {0.f, 0.f, 0.f, 0.f};

  // ---- Pass A: per-lane partial sums of exp(scores) --------------------
  float sume[2][4];
#pragma unroll
  for (int gi = 0; gi < 2; ++gi)
#pragma unroll
    for (int r = 0; r < 4; ++r) sume[gi][r] = 0.f;

  for (int mc = 0; mc < NN / 32; ++mc) {
    const int m0 = mc << 5;
    const bf16x8 hb0 = *(const bf16x8*)(hbase + (size_t)(m0 + lm) * NA + lh * 8);
    const bf16x8 hb1 = *(const bf16x8*)(hbase + (size_t)(m0 + 16 + lm) * NA + lh * 8);
#pragma unroll
    for (int gi = 0; gi < 2; ++gi) {
      const f32x4 s0 = __builtin_amdgcn_mfma_f32_16x16x32_bf16(ga[gi], hb0, zz, 0, 0, 0);
      const f32x4 s1 = __builtin_amdgcn_mfma_f32_16x16x32_bf16(ga[gi], hb1, zz, 0, 0, 0);
#pragma unroll
      for (int r = 0; r < 4; ++r) sume[gi][r] += __expf(s0[r]) + __expf(s1[r]);
    }
  }

  // row-sum across the 16 lanes of each subgroup
  float Linv[2][4];
#pragma unroll
  for (int gi = 0; gi < 2; ++gi)
#pragma unroll
    for (int r = 0; r < 4; ++r) {
      float s = sume[gi][r];
      s += __shfl_xor(s, 1);
      s += __shfl_xor(s, 2);
      s += __shfl_xor(s, 4);
      s += __shfl_xor(s, 8);
      Linv[gi][r] = 1.0f / s;
    }

  // ---- Pass B: alpha write + r accumulation ----------------------------
  f32x4 racc[2][4];
#pragma unroll
  for (int gi = 0; gi < 2; ++gi)
#pragma unroll
    for (int ci = 0; ci < 4; ++ci) racc[gi][ci] = zz;

  float* alpha_n0 = alpha + (size_t)b * NN * NN + (size_t)n0 * NN;

  for (int mc = 0; mc < NN / 32; ++mc) {
    const int m0 = mc << 5;
    const int buf = mc & 1;
    const bf16x8 hb0 = *(const bf16x8*)(hbase + (size_t)(m0 + lm) * NA + lh * 8);
    const bf16x8 hb1 = *(const bf16x8*)(hbase + (size_t)(m0 + 16 + lm) * NA + lh * 8);
#pragma unroll
    for (int gi = 0; gi < 2; ++gi) {
      const f32x4 s0 = __builtin_amdgcn_mfma_f32_16x16x32_bf16(ga[gi], hb0, zz, 0, 0, 0);
      const f32x4 s1 = __builtin_amdgcn_mfma_f32_16x16x32_bf16(ga[gi], hb1, zz, 0, 0, 0);
#pragma unroll
      for (int r = 0; r < 4; ++r) {
        const int row = gi * 16 + lh * 4 + r;
        const float p0 = __expf(s0[r]) * Linv[gi][r];
        const float p1 = __expf(s1[r]) * Linv[gi][r];
        alpha_n0[(size_t)row * NN + m0 + lm]      = p0;
        alpha_n0[(size_t)row * NN + m0 + 16 + lm] = p1;
        p_lds[buf][row][lm]      = f2bf(p0);
        p_lds[buf][row][16 + lm] = f2bf(p1);
      }
    }
    __syncthreads();
    const bf16x8 pa0 = *(const bf16x8*)&p_lds[buf][lm][lh * 8];
    const bf16x8 pa1 = *(const bf16x8*)&p_lds[buf][16 + lm][lh * 8];
#pragma unroll
    for (int ci = 0; ci < 4; ++ci) {
      const bf16x8 xv = *(const bf16x8*)(xbase + (size_t)(ci * 16 + lm) * NN + m0 + lh * 8);
      racc[0][ci] = __builtin_amdgcn_mfma_f32_16x16x32_bf16(pa0, xv, racc[0][ci], 0, 0, 0);
      racc[1][ci] = __builtin_amdgcn_mfma_f32_16x16x32_bf16(pa1, xv, racc[1][ci], 0, 0, 0);
    }
  }

  // ---- epilogue: out = relu(r + x) -------------------------------------
  const float* xres = x + (size_t)b * NC * NN;
  float* outb = outp + (size_t)b * NC * NN;
#pragma unroll
  for (int gi = 0; gi < 2; ++gi)
#pragma unroll
    for (int ci = 0; ci < 4; ++ci)
#pragma unroll
      for (int r = 0; r < 4; ++r) {
        const int nn = n0 + gi * 16 + lh * 4 + r;
        const int c  = ci * 16 + lm;
        const size_t idx = (size_t)c * NN + nn;
        const float v = racc[gi][ci][r] + xres[idx];
        outb[idx] = v > 0.f ? v : 0.f;
      }
}

// ---------------------------------------------------------------------------
extern "C" void kernel_launch(void* const* d_in, const int* in_sizes, int n_in,
                              void* d_out, int out_size, void* d_ws, size_t ws_size,
                              hipStream_t stream) {
  const float* x  = (const float*)d_in[0];
  const float* Wg = (const float*)d_in[1];
  const float* bg = (const float*)d_in[2];
  const float* Wh = (const float*)d_in[3];
  const float* bh = (const float*)d_in[4];

  float* outp  = (float*)d_out;
  float* alpha = outp + (size_t)NB * NC * NN;   // outputs: relu(r) then alpha

  // workspace: gT (2MB) | hqT (2MB) | xfb (4MB)  -- needs ws_size >= 8MB
  ushort* gT  = (ushort*)d_ws;
  ushort* hqT = gT + (size_t)NB * NN * NA;
  ushort* xfb = hqT + (size_t)NB * NN * NA;

  prep_kernel<<<NB * NN / 256, 256, 0, stream>>>(x, Wg, bg, Wh, bh, gT, hqT, xfb);
  attn_kernel<<<NB * (NN / 32), 64, 0, stream>>>(gT, hqT, xfb, x, outp, alpha);
}

// Round 2
// 252.385 us; speedup vs baseline: 1.5302x; 1.5302x over previous
//
#include <hip/hip_runtime.h>
#include <hip/hip_bf16.h>

// Sizes fixed by the problem
#define NB 8
#define NC 64
#define NA 32
#define NN 4096
#define NWAVE 8     // waves per block; each owns an m-chunk of NN/NWAVE = 512

typedef __attribute__((ext_vector_type(8))) short bf16x8;
typedef __attribute__((ext_vector_type(4))) float f32x4;

__device__ inline ushort f2bf(float f) {
  union { float f; unsigned u; } v; v.f = f;
  unsigned r = v.u + 0x7fffu + ((v.u >> 16) & 1u);
  return (ushort)(r >> 16);
}

__device__ inline uint2 packbf(const f32x4 p) {
  uint2 q;
  q.x = (uint)f2bf(p[0]) | ((uint)f2bf(p[1]) << 16);
  q.y = (uint)f2bf(p[2]) | ((uint)f2bf(p[3]) << 16);
  return q;
}

// ---------------------------------------------------------------------------
// Kernel 1: g = Wg@x + bg, hq = Wh@x + bh  (1x1 conv == GEMM)
// Writes bf16: gT[b][n][a], hqT[b][n][a]  (K=a contiguous for MFMA frags)
// and xfb[b][c][n] = bf16(x).
// ---------------------------------------------------------------------------
__global__ __launch_bounds__(256) void prep_kernel(
    const float* __restrict__ x, const float* __restrict__ Wg, const float* __restrict__ bg,
    const float* __restrict__ Wh, const float* __restrict__ bh,
    ushort* __restrict__ gT, ushort* __restrict__ hqT, ushort* __restrict__ xfb)
{
  __shared__ float wg_s[NA * NC];
  __shared__ float wh_s[NA * NC];
  const int t = threadIdx.x;
  for (int i = t; i < NA * NC; i += 256) { wg_s[i] = Wg[i]; wh_s[i] = Wh[i]; }
  __syncthreads();

  const int gid = blockIdx.x * 256 + t;
  const int b = gid >> 12;          // / NN
  const int n = gid & (NN - 1);
  const float* xb = x + (size_t)b * NC * NN + n;

  float accg[NA], acch[NA];
#pragma unroll
  for (int a = 0; a < NA; ++a) { accg[a] = 0.f; acch[a] = 0.f; }

  for (int c4 = 0; c4 < NC / 4; ++c4) {
    const float xv0 = xb[(size_t)(c4 * 4 + 0) * NN];
    const float xv1 = xb[(size_t)(c4 * 4 + 1) * NN];
    const float xv2 = xb[(size_t)(c4 * 4 + 2) * NN];
    const float xv3 = xb[(size_t)(c4 * 4 + 3) * NN];
    const size_t xo = ((size_t)b * NC + c4 * 4) * NN + n;
    xfb[xo]          = f2bf(xv0);
    xfb[xo + NN]     = f2bf(xv1);
    xfb[xo + 2 * NN] = f2bf(xv2);
    xfb[xo + 3 * NN] = f2bf(xv3);
#pragma unroll
    for (int a = 0; a < NA; ++a) {
      const float4 wg4 = *(const float4*)&wg_s[a * NC + c4 * 4];
      const float4 wh4 = *(const float4*)&wh_s[a * NC + c4 * 4];
      accg[a] += wg4.x * xv0 + wg4.y * xv1 + wg4.z * xv2 + wg4.w * xv3;
      acch[a] += wh4.x * xv0 + wh4.y * xv1 + wh4.z * xv2 + wh4.w * xv3;
    }
  }

  ushort og[NA], oh[NA];
#pragma unroll
  for (int a = 0; a < NA; ++a) {
    og[a] = f2bf(accg[a] + bg[a]);
    oh[a] = f2bf(acch[a] + bh[a]);
  }
  const size_t o = ((size_t)b * NN + n) * NA;
#pragma unroll
  for (int k = 0; k < 4; ++k) {
    uint4 vg, vh;
    vg.x = (uint)og[k*8+0] | ((uint)og[k*8+1] << 16);
    vg.y = (uint)og[k*8+2] | ((uint)og[k*8+3] << 16);
    vg.z = (uint)og[k*8+4] | ((uint)og[k*8+5] << 16);
    vg.w = (uint)og[k*8+6] | ((uint)og[k*8+7] << 16);
    vh.x = (uint)oh[k*8+0] | ((uint)oh[k*8+1] << 16);
    vh.y = (uint)oh[k*8+2] | ((uint)oh[k*8+3] << 16);
    vh.z = (uint)oh[k*8+4] | ((uint)oh[k*8+5] << 16);
    vh.w = (uint)oh[k*8+6] | ((uint)oh[k*8+7] << 16);
    *(uint4*)(gT  + o + k * 8) = vg;
    *(uint4*)(hqT + o + k * 8) = vh;
  }
}

// ---------------------------------------------------------------------------
// Kernel 2: block = (b, 32-row n-tile). 8 waves; wave w owns m in
// [w*512, w*512+512). Transposed-score MFMA: s_t = mfma(A=hq, B=g) gives
// lane = (m = lh*4+r  [4 consecutive m], n = lm) -> float4 alpha stores.
// Phase 1: per-wave partial row sums of exp -> LDS -> block-combined Linv.
// Phase 2: recompute scores, p=exp*Linv, float4 alpha write, p->LDS (b64),
//          r-GEMM racc[n][c] += mfma(p, x).
// Phase 3: block r-reduction via LDS atomicAdd, transposed coalesced epilogue.
// ---------------------------------------------------------------------------
__global__ __launch_bounds__(512, 4) void attn_kernel(
    const ushort* __restrict__ gT, const ushort* __restrict__ hqT,
    const ushort* __restrict__ xfb, const float* __restrict__ x,
    float* __restrict__ outp, float* __restrict__ alpha)
{
  __shared__ ushort pbuf[NWAVE][32][36];  // per-wave p staging, stride 36 shorts
  __shared__ float rtile[32][65];         // block r accumulator [n][c], pad 65
  __shared__ float Lp[NWAVE][32];         // per-wave partial row sums

  const int tid = threadIdx.x;
  const int l  = tid & 63;
  const int w  = tid >> 6;
  const int lm = l & 15;
  const int lh = l >> 4;
  const int b  = blockIdx.x >> 7;
  const int n0 = (blockIdx.x & 127) << 5;
  const int mbase = w << 9;               // 512 m per wave

  // zero the block r accumulator (completes before the phase-1 barrier)
  float* rflat = &rtile[0][0];
  for (int i = tid; i < 32 * 65; i += 512) rflat[i] = 0.f;

  const ushort* gB = gT  + (size_t)b * NN * NA;
  const ushort* hB = hqT + (size_t)b * NN * NA;
  const ushort* xB = xfb + (size_t)b * NC * NN;

  bf16x8 gb0 = *(const bf16x8*)(gB + (size_t)(n0 + lm) * NA + lh * 8);
  bf16x8 gb1 = *(const bf16x8*)(gB + (size_t)(n0 + 16 + lm) * NA + lh * 8);

  const f32x4 zz = {0.f, 0.f, 0.f, 0.f};

  // ---- Phase 1: partial sums of exp(scores) over this wave's m-chunk ----
  float sume0 = 0.f, sume1 = 0.f;
  for (int mc = 0; mc < 16; ++mc) {
    const int m0 = mbase + (mc << 5);
    const bf16x8 ha0 = *(const bf16x8*)(hB + (size_t)(m0 + lm) * NA + lh * 8);
    const bf16x8 ha1 = *(const bf16x8*)(hB + (size_t)(m0 + 16 + lm) * NA + lh * 8);
    const f32x4 s00 = __builtin_amdgcn_mfma_f32_16x16x32_bf16(ha0, gb0, zz, 0, 0, 0);
    const f32x4 s10 = __builtin_amdgcn_mfma_f32_16x16x32_bf16(ha1, gb0, zz, 0, 0, 0);
    const f32x4 s01 = __builtin_amdgcn_mfma_f32_16x16x32_bf16(ha0, gb1, zz, 0, 0, 0);
    const f32x4 s11 = __builtin_amdgcn_mfma_f32_16x16x32_bf16(ha1, gb1, zz, 0, 0, 0);
#pragma unroll
    for (int r = 0; r < 4; ++r) {
      sume0 += __expf(s00[r]) + __expf(s10[r]);
      sume1 += __expf(s01[r]) + __expf(s11[r]);
    }
  }
  // lanes lh=0..3 (same lm) partition m -> sum them
  sume0 += __shfl_xor(sume0, 16); sume0 += __shfl_xor(sume0, 32);
  sume1 += __shfl_xor(sume1, 16); sume1 += __shfl_xor(sume1, 32);
  if (l < 16) { Lp[w][l] = sume0; Lp[w][16 + l] = sume1; }
  __syncthreads();

  float Ls0 = 0.f, Ls1 = 0.f;
#pragma unroll
  for (int ww = 0; ww < NWAVE; ++ww) { Ls0 += Lp[ww][lm]; Ls1 += Lp[ww][16 + lm]; }
  const float Linv0 = 1.0f / Ls0;
  const float Linv1 = 1.0f / Ls1;

  // ---- Phase 2: alpha write + r accumulation ----------------------------
  f32x4 racc[2][4];
#pragma unroll
  for (int gi = 0; gi < 2; ++gi)
#pragma unroll
    for (int ci = 0; ci < 4; ++ci) racc[gi][ci] = zz;

  float* aB = alpha + ((size_t)b * NN + n0) * NN;

  for (int mc = 0; mc < 16; ++mc) {
    const int m0 = mbase + (mc << 5);
    const bf16x8 ha0 = *(const bf16x8*)(hB + (size_t)(m0 + lm) * NA + lh * 8);
    const bf16x8 ha1 = *(const bf16x8*)(hB + (size_t)(m0 + 16 + lm) * NA + lh * 8);
    const f32x4 s00 = __builtin_amdgcn_mfma_f32_16x16x32_bf16(ha0, gb0, zz, 0, 0, 0);
    const f32x4 s10 = __builtin_amdgcn_mfma_f32_16x16x32_bf16(ha1, gb0, zz, 0, 0, 0);
    const f32x4 s01 = __builtin_amdgcn_mfma_f32_16x16x32_bf16(ha0, gb1, zz, 0, 0, 0);
    const f32x4 s11 = __builtin_amdgcn_mfma_f32_16x16x32_bf16(ha1, gb1, zz, 0, 0, 0);

    f32x4 p00, p10, p01, p11;
#pragma unroll
    for (int r = 0; r < 4; ++r) {
      p00[r] = __expf(s00[r]) * Linv0;
      p10[r] = __expf(s10[r]) * Linv0;
      p01[r] = __expf(s01[r]) * Linv1;
      p11[r] = __expf(s11[r]) * Linv1;
    }

    // alpha[n][m]: lane writes 4 consecutive m for its n -> float4 stores
    *(f32x4*)(aB + (size_t)lm * NN        + m0 + lh * 4)      = p00;
    *(f32x4*)(aB + (size_t)lm * NN        + m0 + 16 + lh * 4) = p10;
    *(f32x4*)(aB + (size_t)(16 + lm) * NN + m0 + lh * 4)      = p01;
    *(f32x4*)(aB + (size_t)(16 + lm) * NN + m0 + 16 + lh * 4) = p11;

    // stage p (bf16) into this wave's private LDS region: pbuf[w][n][m_local]
    *(uint2*)&pbuf[w][lm][lh * 4]           = packbf(p00);
    *(uint2*)&pbuf[w][lm][16 + lh * 4]      = packbf(p10);
    *(uint2*)&pbuf[w][16 + lm][lh * 4]      = packbf(p01);
    *(uint2*)&pbuf[w][16 + lm][16 + lh * 4] = packbf(p11);

    // A-frags for r-GEMM: lane needs p[n = lm (+16)][m = lh*8 .. +7]
    union UB { uint4 u; bf16x8 v; } ua, ub;
    {
      const uint2 a0 = *(const uint2*)&pbuf[w][lm][lh * 8];
      const uint2 a1 = *(const uint2*)&pbuf[w][lm][lh * 8 + 4];
      ua.u = make_uint4(a0.x, a0.y, a1.x, a1.y);
      const uint2 b0 = *(const uint2*)&pbuf[w][16 + lm][lh * 8];
      const uint2 b1 = *(const uint2*)&pbuf[w][16 + lm][lh * 8 + 4];
      ub.u = make_uint4(b0.x, b0.y, b1.x, b1.y);
    }
    const bf16x8 pa0 = ua.v;
    const bf16x8 pa1 = ub.v;

#pragma unroll
    for (int ci = 0; ci < 4; ++ci) {
      const bf16x8 xv = *(const bf16x8*)(xB + (size_t)(ci * 16 + lm) * NN + m0 + lh * 8);
      racc[0][ci] = __builtin_amdgcn_mfma_f32_16x16x32_bf16(pa0, xv, racc[0][ci], 0, 0, 0);
      racc[1][ci] = __builtin_amdgcn_mfma_f32_16x16x32_bf16(pa1, xv, racc[1][ci], 0, 0, 0);
    }
  }

  // ---- Phase 3: reduce partial r across waves ---------------------------
#pragma unroll
  for (int gi = 0; gi < 2; ++gi)
#pragma unroll
    for (int ci = 0; ci < 4; ++ci)
#pragma unroll
      for (int r = 0; r < 4; ++r)
        atomicAdd(&rtile[gi * 16 + lh * 4 + r][ci * 16 + lm], racc[gi][ci][r]);
  __syncthreads();

  // epilogue: out[b][c][n] = relu(r + x), fully coalesced float4
  const int c  = tid >> 3;
  const int j4 = (tid & 7) << 2;
  f32x4 v;
#pragma unroll
  for (int k = 0; k < 4; ++k) v[k] = rtile[j4 + k][c];
  const size_t oo = ((size_t)b * NC + c) * NN + n0 + j4;
  const f32x4 xr = *(const f32x4*)(x + oo);
#pragma unroll
  for (int k = 0; k < 4; ++k) {
    const float t = v[k] + xr[k];
    v[k] = t > 0.f ? t : 0.f;
  }
  *(f32x4*)(outp + oo) = v;
}

// ---------------------------------------------------------------------------
extern "C" void kernel_launch(void* const* d_in, const int* in_sizes, int n_in,
                              void* d_out, int out_size, void* d_ws, size_t ws_size,
                              hipStream_t stream) {
  const float* x  = (const float*)d_in[0];
  const float* Wg = (const float*)d_in[1];
  const float* bg = (const float*)d_in[2];
  const float* Wh = (const float*)d_in[3];
  const float* bh = (const float*)d_in[4];

  float* outp  = (float*)d_out;
  float* alpha = outp + (size_t)NB * NC * NN;   // outputs: relu(r) then alpha

  // workspace: gT (2MB) | hqT (2MB) | xfb (4MB)
  ushort* gT  = (ushort*)d_ws;
  ushort* hqT = gT + (size_t)NB * NN * NA;
  ushort* xfb = hqT + (size_t)NB * NN * NA;

  prep_kernel<<<NB * NN / 256, 256, 0, stream>>>(x, Wg, bg, Wh, bh, gT, hqT, xfb);
  attn_kernel<<<NB * (NN / 32), 512, 0, stream>>>(gT, hqT, xfb, x, outp, alpha);
}

// Round 3
// 235.275 us; speedup vs baseline: 1.6415x; 1.0727x over previous
//
#include <hip/hip_runtime.h>
#include <hip/hip_bf16.h>
#include <math.h>

// Sizes fixed by the problem
#define NB 8
#define NC 64
#define NA 32
#define NN 4096
#define NWAVE 8     // waves per block; each owns an m-chunk of NN/NWAVE = 512

typedef __attribute__((ext_vector_type(8))) short bf16x8;
typedef __attribute__((ext_vector_type(4))) float f32x4;

__device__ inline ushort f2bf(float f) {
  union { float f; unsigned u; } v; v.f = f;
  unsigned r = v.u + 0x7fffu + ((v.u >> 16) & 1u);
  return (ushort)(r >> 16);
}

__device__ inline uint2 packbf(const f32x4 p) {
  uint2 q;
  q.x = (uint)f2bf(p[0]) | ((uint)f2bf(p[1]) << 16);
  q.y = (uint)f2bf(p[2]) | ((uint)f2bf(p[3]) << 16);
  return q;
}

// ---------------------------------------------------------------------------
// Kernel 1: g = (Wg@x + bg) * log2(e)  [folded so scores feed exp2 directly],
//           hq = Wh@x + bh.
// Writes bf16: gT[b][n][a], hqT[b][n][a]  (K=a contiguous for MFMA frags)
// and xfb[b][c][n] = bf16(x).
// ---------------------------------------------------------------------------
__global__ __launch_bounds__(256) void prep_kernel(
    const float* __restrict__ x, const float* __restrict__ Wg, const float* __restrict__ bg,
    const float* __restrict__ Wh, const float* __restrict__ bh,
    ushort* __restrict__ gT, ushort* __restrict__ hqT, ushort* __restrict__ xfb)
{
  __shared__ float wg_s[NA * NC];
  __shared__ float wh_s[NA * NC];
  const int t = threadIdx.x;
  for (int i = t; i < NA * NC; i += 256) { wg_s[i] = Wg[i]; wh_s[i] = Wh[i]; }
  __syncthreads();

  const int gid = blockIdx.x * 256 + t;
  const int b = gid >> 12;          // / NN
  const int n = gid & (NN - 1);
  const float* xb = x + (size_t)b * NC * NN + n;

  float accg[NA], acch[NA];
#pragma unroll
  for (int a = 0; a < NA; ++a) { accg[a] = 0.f; acch[a] = 0.f; }

  for (int c4 = 0; c4 < NC / 4; ++c4) {
    const float xv0 = xb[(size_t)(c4 * 4 + 0) * NN];
    const float xv1 = xb[(size_t)(c4 * 4 + 1) * NN];
    const float xv2 = xb[(size_t)(c4 * 4 + 2) * NN];
    const float xv3 = xb[(size_t)(c4 * 4 + 3) * NN];
    const size_t xo = ((size_t)b * NC + c4 * 4) * NN + n;
    xfb[xo]          = f2bf(xv0);
    xfb[xo + NN]     = f2bf(xv1);
    xfb[xo + 2 * NN] = f2bf(xv2);
    xfb[xo + 3 * NN] = f2bf(xv3);
#pragma unroll
    for (int a = 0; a < NA; ++a) {
      const float4 wg4 = *(const float4*)&wg_s[a * NC + c4 * 4];
      const float4 wh4 = *(const float4*)&wh_s[a * NC + c4 * 4];
      accg[a] += wg4.x * xv0 + wg4.y * xv1 + wg4.z * xv2 + wg4.w * xv3;
      acch[a] += wh4.x * xv0 + wh4.y * xv1 + wh4.z * xv2 + wh4.w * xv3;
    }
  }

  const float LOG2E = 1.44269504088896340736f;
  ushort og[NA], oh[NA];
#pragma unroll
  for (int a = 0; a < NA; ++a) {
    og[a] = f2bf((accg[a] + bg[a]) * LOG2E);   // fold log2(e) into g
    oh[a] = f2bf(acch[a] + bh[a]);
  }
  const size_t o = ((size_t)b * NN + n) * NA;
#pragma unroll
  for (int k = 0; k < 4; ++k) {
    uint4 vg, vh;
    vg.x = (uint)og[k*8+0] | ((uint)og[k*8+1] << 16);
    vg.y = (uint)og[k*8+2] | ((uint)og[k*8+3] << 16);
    vg.z = (uint)og[k*8+4] | ((uint)og[k*8+5] << 16);
    vg.w = (uint)og[k*8+6] | ((uint)og[k*8+7] << 16);
    vh.x = (uint)oh[k*8+0] | ((uint)oh[k*8+1] << 16);
    vh.y = (uint)oh[k*8+2] | ((uint)oh[k*8+3] << 16);
    vh.z = (uint)oh[k*8+4] | ((uint)oh[k*8+5] << 16);
    vh.w = (uint)oh[k*8+6] | ((uint)oh[k*8+7] << 16);
    *(uint4*)(gT  + o + k * 8) = vg;
    *(uint4*)(hqT + o + k * 8) = vh;
  }
}

// ---------------------------------------------------------------------------
// Kernel 2: block = (b, 32-row n-tile). 8 waves; wave w owns m-chunk of 512.
// scores(transposed) = mfma(A=hq, B=g): lane=(m=lh*4+r, n=lm).
// Phase 1: per-wave partial row sums of exp2 -> LDS -> block Linv.
// Phase 2: recompute, p = exp2(s)*Linv, NT float4 alpha write, p->LDS,
//          r-GEMM racc += mfma(p, x).   ha loads software-pipelined.
// Phase 3: LDS atomic r-reduction, transposed coalesced NT epilogue.
// ---------------------------------------------------------------------------
__global__ __launch_bounds__(512, 4) void attn_kernel(
    const ushort* __restrict__ gT, const ushort* __restrict__ hqT,
    const ushort* __restrict__ xfb, const float* __restrict__ x,
    float* __restrict__ outp, float* __restrict__ alpha)
{
  __shared__ ushort pbuf[NWAVE][32][36];  // per-wave p staging, stride 36 shorts
  __shared__ float rtile[32][65];         // block r accumulator [n][c]
  __shared__ float Lp[NWAVE][32];         // per-wave partial row sums

  const int tid = threadIdx.x;
  const int l  = tid & 63;
  const int w  = tid >> 6;
  const int lm = l & 15;
  const int lh = l >> 4;
  const int b  = blockIdx.x >> 7;
  const int n0 = (blockIdx.x & 127) << 5;
  const int mbase = w << 9;               // 512 m per wave

  const ushort* gB = gT  + (size_t)b * NN * NA;
  const ushort* hB = hqT + (size_t)b * NN * NA;
  const ushort* xB = xfb + (size_t)b * NC * NN;

  // issue long-latency loads first
  bf16x8 gb0 = *(const bf16x8*)(gB + (size_t)(n0 + lm) * NA + lh * 8);
  bf16x8 gb1 = *(const bf16x8*)(gB + (size_t)(n0 + 16 + lm) * NA + lh * 8);
  bf16x8 ha0 = *(const bf16x8*)(hB + (size_t)(mbase + lm) * NA + lh * 8);
  bf16x8 ha1 = *(const bf16x8*)(hB + (size_t)(mbase + 16 + lm) * NA + lh * 8);

  // zero the block r accumulator (completes before the phase-1 barrier)
  float* rflat = &rtile[0][0];
  for (int i = tid; i < 32 * 65; i += 512) rflat[i] = 0.f;

  const f32x4 zz = {0.f, 0.f, 0.f, 0.f};

  // ---- Phase 1: partial sums of exp2(scores) over this wave's m-chunk ----
  float sume0 = 0.f, sume1 = 0.f;
  for (int mc = 0; mc < 16; ++mc) {
    // prefetch next iteration's ha (wraps harmlessly on last iter)
    const int m1 = mbase + (((mc + 1) & 15) << 5);
    const bf16x8 na0 = *(const bf16x8*)(hB + (size_t)(m1 + lm) * NA + lh * 8);
    const bf16x8 na1 = *(const bf16x8*)(hB + (size_t)(m1 + 16 + lm) * NA + lh * 8);

    const f32x4 s00 = __builtin_amdgcn_mfma_f32_16x16x32_bf16(ha0, gb0, zz, 0, 0, 0);
    const f32x4 s10 = __builtin_amdgcn_mfma_f32_16x16x32_bf16(ha1, gb0, zz, 0, 0, 0);
    const f32x4 s01 = __builtin_amdgcn_mfma_f32_16x16x32_bf16(ha0, gb1, zz, 0, 0, 0);
    const f32x4 s11 = __builtin_amdgcn_mfma_f32_16x16x32_bf16(ha1, gb1, zz, 0, 0, 0);
#pragma unroll
    for (int r = 0; r < 4; ++r) {
      sume0 += exp2f(s00[r]) + exp2f(s10[r]);
      sume1 += exp2f(s01[r]) + exp2f(s11[r]);
    }
    ha0 = na0; ha1 = na1;
  }
  sume0 += __shfl_xor(sume0, 16); sume0 += __shfl_xor(sume0, 32);
  sume1 += __shfl_xor(sume1, 16); sume1 += __shfl_xor(sume1, 32);
  if (l < 16) { Lp[w][l] = sume0; Lp[w][16 + l] = sume1; }
  __syncthreads();

  float Ls0 = 0.f, Ls1 = 0.f;
#pragma unroll
  for (int ww = 0; ww < NWAVE; ++ww) { Ls0 += Lp[ww][lm]; Ls1 += Lp[ww][16 + lm]; }
  const float Linv0 = 1.0f / Ls0;
  const float Linv1 = 1.0f / Ls1;

  // ---- Phase 2: alpha write + r accumulation ----------------------------
  f32x4 racc[2][4];
#pragma unroll
  for (int gi = 0; gi < 2; ++gi)
#pragma unroll
    for (int ci = 0; ci < 4; ++ci) racc[gi][ci] = zz;

  float* aB = alpha + ((size_t)b * NN + n0) * NN;

  for (int mc = 0; mc < 16; ++mc) {
    const int m0 = mbase + (mc << 5);
    const int m1 = mbase + (((mc + 1) & 15) << 5);
    const bf16x8 na0 = *(const bf16x8*)(hB + (size_t)(m1 + lm) * NA + lh * 8);
    const bf16x8 na1 = *(const bf16x8*)(hB + (size_t)(m1 + 16 + lm) * NA + lh * 8);

    const f32x4 s00 = __builtin_amdgcn_mfma_f32_16x16x32_bf16(ha0, gb0, zz, 0, 0, 0);
    const f32x4 s10 = __builtin_amdgcn_mfma_f32_16x16x32_bf16(ha1, gb0, zz, 0, 0, 0);
    const f32x4 s01 = __builtin_amdgcn_mfma_f32_16x16x32_bf16(ha0, gb1, zz, 0, 0, 0);
    const f32x4 s11 = __builtin_amdgcn_mfma_f32_16x16x32_bf16(ha1, gb1, zz, 0, 0, 0);

    f32x4 p00, p10, p01, p11;
#pragma unroll
    for (int r = 0; r < 4; ++r) {
      p00[r] = exp2f(s00[r]) * Linv0;
      p10[r] = exp2f(s10[r]) * Linv0;
      p01[r] = exp2f(s01[r]) * Linv1;
      p11[r] = exp2f(s11[r]) * Linv1;
    }

    // alpha[n][m]: nontemporal float4 stores (streaming, never re-read)
    __builtin_nontemporal_store(p00, (f32x4*)(aB + (size_t)lm * NN        + m0 + lh * 4));
    __builtin_nontemporal_store(p10, (f32x4*)(aB + (size_t)lm * NN        + m0 + 16 + lh * 4));
    __builtin_nontemporal_store(p01, (f32x4*)(aB + (size_t)(16 + lm) * NN + m0 + lh * 4));
    __builtin_nontemporal_store(p11, (f32x4*)(aB + (size_t)(16 + lm) * NN + m0 + 16 + lh * 4));

    // stage p (bf16) into this wave's private LDS region
    *(uint2*)&pbuf[w][lm][lh * 4]           = packbf(p00);
    *(uint2*)&pbuf[w][lm][16 + lh * 4]      = packbf(p10);
    *(uint2*)&pbuf[w][16 + lm][lh * 4]      = packbf(p01);
    *(uint2*)&pbuf[w][16 + lm][16 + lh * 4] = packbf(p11);

    // A-frags for r-GEMM: lane needs p[n = lm (+16)][m = lh*8 .. +7]
    union UB { uint4 u; bf16x8 v; } ua, ub;
    {
      const uint2 a0 = *(const uint2*)&pbuf[w][lm][lh * 8];
      const uint2 a1 = *(const uint2*)&pbuf[w][lm][lh * 8 + 4];
      ua.u = make_uint4(a0.x, a0.y, a1.x, a1.y);
      const uint2 b0 = *(const uint2*)&pbuf[w][16 + lm][lh * 8];
      const uint2 b1 = *(const uint2*)&pbuf[w][16 + lm][lh * 8 + 4];
      ub.u = make_uint4(b0.x, b0.y, b1.x, b1.y);
    }
    const bf16x8 pa0 = ua.v;
    const bf16x8 pa1 = ub.v;

#pragma unroll
    for (int ci = 0; ci < 4; ++ci) {
      const bf16x8 xv = *(const bf16x8*)(xB + (size_t)(ci * 16 + lm) * NN + m0 + lh * 8);
      racc[0][ci] = __builtin_amdgcn_mfma_f32_16x16x32_bf16(pa0, xv, racc[0][ci], 0, 0, 0);
      racc[1][ci] = __builtin_amdgcn_mfma_f32_16x16x32_bf16(pa1, xv, racc[1][ci], 0, 0, 0);
    }
    ha0 = na0; ha1 = na1;
  }

  // ---- Phase 3: reduce partial r across waves ---------------------------
#pragma unroll
  for (int gi = 0; gi < 2; ++gi)
#pragma unroll
    for (int ci = 0; ci < 4; ++ci)
#pragma unroll
      for (int r = 0; r < 4; ++r)
        atomicAdd(&rtile[gi * 16 + lh * 4 + r][ci * 16 + lm], racc[gi][ci][r]);
  __syncthreads();

  // epilogue: out[b][c][n] = relu(r + x), coalesced NT float4
  const int c  = tid >> 3;
  const int j4 = (tid & 7) << 2;
  f32x4 v;
#pragma unroll
  for (int k = 0; k < 4; ++k) v[k] = rtile[j4 + k][c];
  const size_t oo = ((size_t)b * NC + c) * NN + n0 + j4;
  const f32x4 xr = *(const f32x4*)(x + oo);
#pragma unroll
  for (int k = 0; k < 4; ++k) {
    const float t = v[k] + xr[k];
    v[k] = t > 0.f ? t : 0.f;
  }
  __builtin_nontemporal_store(v, (f32x4*)(outp + oo));
}

// ---------------------------------------------------------------------------
extern "C" void kernel_launch(void* const* d_in, const int* in_sizes, int n_in,
                              void* d_out, int out_size, void* d_ws, size_t ws_size,
                              hipStream_t stream) {
  const float* x  = (const float*)d_in[0];
  const float* Wg = (const float*)d_in[1];
  const float* bg = (const float*)d_in[2];
  const float* Wh = (const float*)d_in[3];
  const float* bh = (const float*)d_in[4];

  float* outp  = (float*)d_out;
  float* alpha = outp + (size_t)NB * NC * NN;   // outputs: relu(r) then alpha

  // workspace: gT (2MB) | hqT (2MB) | xfb (4MB)
  ushort* gT  = (ushort*)d_ws;
  ushort* hqT = gT + (size_t)NB * NN * NA;
  ushort* xfb = hqT + (size_t)NB * NN * NA;

  prep_kernel<<<NB * NN / 256, 256, 0, stream>>>(x, Wg, bg, Wh, bh, gT, hqT, xfb);
  attn_kernel<<<NB * (NN / 32), 512, 0, stream>>>(gT, hqT, xfb, x, outp, alpha);
}

// Round 4
// 227.275 us; speedup vs baseline: 1.6992x; 1.0352x over previous
//
#include <hip/hip_runtime.h>
#include <hip/hip_bf16.h>
#include <math.h>

// Sizes fixed by the problem
#define NB 8
#define NC 64
#define NA 32
#define NN 4096
#define NWAVE 8     // waves per block; each owns an m-chunk of NN/NWAVE = 512

typedef __attribute__((ext_vector_type(8))) short bf16x8;
typedef __attribute__((ext_vector_type(4))) float f32x4;

__device__ inline ushort f2bf(float f) {
  union { float f; unsigned u; } v; v.f = f;
  unsigned r = v.u + 0x7fffu + ((v.u >> 16) & 1u);
  return (ushort)(r >> 16);
}

__device__ inline bf16x8 pack8(const f32x4 a, const f32x4 b) {
  union { ushort us[8]; bf16x8 v; } u;
#pragma unroll
  for (int i = 0; i < 4; ++i) { u.us[i] = f2bf(a[i]); u.us[4 + i] = f2bf(b[i]); }
  return u.v;
}

// ---------------------------------------------------------------------------
// Kernel 1: g = (Wg@x + bg) * log2(e)  [folded so scores feed exp2 directly],
//           hq = Wh@x + bh.
// Writes bf16: gT[b][n][a], hqT[b][n][a]  (K=a contiguous for MFMA frags)
// and xfb[b][c][n] = bf16(x).
// ---------------------------------------------------------------------------
__global__ __launch_bounds__(256) void prep_kernel(
    const float* __restrict__ x, const float* __restrict__ Wg, const float* __restrict__ bg,
    const float* __restrict__ Wh, const float* __restrict__ bh,
    ushort* __restrict__ gT, ushort* __restrict__ hqT, ushort* __restrict__ xfb)
{
  __shared__ float wg_s[NA * NC];
  __shared__ float wh_s[NA * NC];
  const int t = threadIdx.x;
  for (int i = t; i < NA * NC; i += 256) { wg_s[i] = Wg[i]; wh_s[i] = Wh[i]; }
  __syncthreads();

  const int gid = blockIdx.x * 256 + t;
  const int b = gid >> 12;          // / NN
  const int n = gid & (NN - 1);
  const float* xb = x + (size_t)b * NC * NN + n;

  float accg[NA], acch[NA];
#pragma unroll
  for (int a = 0; a < NA; ++a) { accg[a] = 0.f; acch[a] = 0.f; }

  for (int c4 = 0; c4 < NC / 4; ++c4) {
    const float xv0 = xb[(size_t)(c4 * 4 + 0) * NN];
    const float xv1 = xb[(size_t)(c4 * 4 + 1) * NN];
    const float xv2 = xb[(size_t)(c4 * 4 + 2) * NN];
    const float xv3 = xb[(size_t)(c4 * 4 + 3) * NN];
    const size_t xo = ((size_t)b * NC + c4 * 4) * NN + n;
    xfb[xo]          = f2bf(xv0);
    xfb[xo + NN]     = f2bf(xv1);
    xfb[xo + 2 * NN] = f2bf(xv2);
    xfb[xo + 3 * NN] = f2bf(xv3);
#pragma unroll
    for (int a = 0; a < NA; ++a) {
      const float4 wg4 = *(const float4*)&wg_s[a * NC + c4 * 4];
      const float4 wh4 = *(const float4*)&wh_s[a * NC + c4 * 4];
      accg[a] += wg4.x * xv0 + wg4.y * xv1 + wg4.z * xv2 + wg4.w * xv3;
      acch[a] += wh4.x * xv0 + wh4.y * xv1 + wh4.z * xv2 + wh4.w * xv3;
    }
  }

  const float LOG2E = 1.44269504088896340736f;
  ushort og[NA], oh[NA];
#pragma unroll
  for (int a = 0; a < NA; ++a) {
    og[a] = f2bf((accg[a] + bg[a]) * LOG2E);   // fold log2(e) into g
    oh[a] = f2bf(acch[a] + bh[a]);
  }
  const size_t o = ((size_t)b * NN + n) * NA;
#pragma unroll
  for (int k = 0; k < 4; ++k) {
    uint4 vg, vh;
    vg.x = (uint)og[k*8+0] | ((uint)og[k*8+1] << 16);
    vg.y = (uint)og[k*8+2] | ((uint)og[k*8+3] << 16);
    vg.z = (uint)og[k*8+4] | ((uint)og[k*8+5] << 16);
    vg.w = (uint)og[k*8+6] | ((uint)og[k*8+7] << 16);
    vh.x = (uint)oh[k*8+0] | ((uint)oh[k*8+1] << 16);
    vh.y = (uint)oh[k*8+2] | ((uint)oh[k*8+3] << 16);
    vh.z = (uint)oh[k*8+4] | ((uint)oh[k*8+5] << 16);
    vh.w = (uint)oh[k*8+6] | ((uint)oh[k*8+7] << 16);
    *(uint4*)(gT  + o + k * 8) = vg;
    *(uint4*)(hqT + o + k * 8) = vh;
  }
}

// ---------------------------------------------------------------------------
// Kernel 2: block = (b, 32-row n-tile). 8 waves; wave w owns m-chunk of 512.
// scores(transposed) = mfma(A=hq, B=g): lane=(m=lh*4+r, n=lm).
// Phase 1: per-wave partial row sums of exp2 -> LDS -> block Linv.
// Phase 2: recompute, p = exp2(s)*Linv -> per-wave swizzled f32 LDS tile;
//          alpha stored as FULL 128B lines (8 rows x 128B per instr, NT);
//          A-frags re-read from same tile (bf16 convert); r-GEMM mfma(p, x).
// LDS tile: rows of 8 x 16B units, phys unit = u ^ (row&7) -> conflict-free
// for writer (n=lm, u=lh), alpha reader (row=l>>3, u=l&7), frag reader
// (row=lm, u=2lh,2lh+1).
// Phase 3: LDS atomic r-reduction, transposed coalesced NT epilogue.
// ---------------------------------------------------------------------------
__global__ __launch_bounds__(512, 4) void attn_kernel(
    const ushort* __restrict__ gT, const ushort* __restrict__ hqT,
    const ushort* __restrict__ xfb, const float* __restrict__ x,
    float* __restrict__ outp, float* __restrict__ alpha)
{
  __shared__ float plds[NWAVE][32][32];   // per-wave p tile, swizzled 16B units
  __shared__ float rtile[32][65];         // block r accumulator [n][c]
  __shared__ float Lp[NWAVE][32];         // per-wave partial row sums

  const int tid = threadIdx.x;
  const int l  = tid & 63;
  const int w  = tid >> 6;
  const int lm = l & 15;
  const int lh = l >> 4;
  const int b  = blockIdx.x >> 7;
  const int n0 = (blockIdx.x & 127) << 5;
  const int mbase = w << 9;               // 512 m per wave

  const ushort* gB = gT  + (size_t)b * NN * NA;
  const ushort* hB = hqT + (size_t)b * NN * NA;
  const ushort* xB = xfb + (size_t)b * NC * NN;

  // issue long-latency loads first
  bf16x8 gb0 = *(const bf16x8*)(gB + (size_t)(n0 + lm) * NA + lh * 8);
  bf16x8 gb1 = *(const bf16x8*)(gB + (size_t)(n0 + 16 + lm) * NA + lh * 8);
  bf16x8 ha0 = *(const bf16x8*)(hB + (size_t)(mbase + lm) * NA + lh * 8);
  bf16x8 ha1 = *(const bf16x8*)(hB + (size_t)(mbase + 16 + lm) * NA + lh * 8);

  // zero the block r accumulator (completes before the phase-1 barrier)
  float* rflat = &rtile[0][0];
  for (int i = tid; i < 32 * 65; i += 512) rflat[i] = 0.f;

  const f32x4 zz = {0.f, 0.f, 0.f, 0.f};

  // ---- Phase 1: partial sums of exp2(scores) over this wave's m-chunk ----
  float sume0 = 0.f, sume1 = 0.f;
  for (int mc = 0; mc < 16; ++mc) {
    const int m1 = mbase + (((mc + 1) & 15) << 5);
    const bf16x8 na0 = *(const bf16x8*)(hB + (size_t)(m1 + lm) * NA + lh * 8);
    const bf16x8 na1 = *(const bf16x8*)(hB + (size_t)(m1 + 16 + lm) * NA + lh * 8);

    const f32x4 s00 = __builtin_amdgcn_mfma_f32_16x16x32_bf16(ha0, gb0, zz, 0, 0, 0);
    const f32x4 s10 = __builtin_amdgcn_mfma_f32_16x16x32_bf16(ha1, gb0, zz, 0, 0, 0);
    const f32x4 s01 = __builtin_amdgcn_mfma_f32_16x16x32_bf16(ha0, gb1, zz, 0, 0, 0);
    const f32x4 s11 = __builtin_amdgcn_mfma_f32_16x16x32_bf16(ha1, gb1, zz, 0, 0, 0);
#pragma unroll
    for (int r = 0; r < 4; ++r) {
      sume0 += exp2f(s00[r]) + exp2f(s10[r]);
      sume1 += exp2f(s01[r]) + exp2f(s11[r]);
    }
    ha0 = na0; ha1 = na1;
  }
  sume0 += __shfl_xor(sume0, 16); sume0 += __shfl_xor(sume0, 32);
  sume1 += __shfl_xor(sume1, 16); sume1 += __shfl_xor(sume1, 32);
  if (l < 16) { Lp[w][l] = sume0; Lp[w][16 + l] = sume1; }
  __syncthreads();

  float Ls0 = 0.f, Ls1 = 0.f;
#pragma unroll
  for (int ww = 0; ww < NWAVE; ++ww) { Ls0 += Lp[ww][lm]; Ls1 += Lp[ww][16 + lm]; }
  const float Linv0 = 1.0f / Ls0;
  const float Linv1 = 1.0f / Ls1;

  // ---- Phase 2: alpha write + r accumulation ----------------------------
  f32x4 racc[2][4];
#pragma unroll
  for (int gi = 0; gi < 2; ++gi)
#pragma unroll
    for (int ci = 0; ci < 4; ++ci) racc[gi][ci] = zz;

  float* aB = alpha + ((size_t)b * NN + n0) * NN;
  const int k7   = lm & 7;   // swizzle key for rows lm and 16+lm
  const int nrow = l >> 3;   // alpha-store row within 8-row group
  const int uu   = l & 7;    // alpha-store 16B unit

  for (int mc = 0; mc < 16; ++mc) {
    const int m0 = mbase + (mc << 5);
    const int m1 = mbase + (((mc + 1) & 15) << 5);
    const bf16x8 na0 = *(const bf16x8*)(hB + (size_t)(m1 + lm) * NA + lh * 8);
    const bf16x8 na1 = *(const bf16x8*)(hB + (size_t)(m1 + 16 + lm) * NA + lh * 8);

    const f32x4 s00 = __builtin_amdgcn_mfma_f32_16x16x32_bf16(ha0, gb0, zz, 0, 0, 0);
    const f32x4 s10 = __builtin_amdgcn_mfma_f32_16x16x32_bf16(ha1, gb0, zz, 0, 0, 0);
    const f32x4 s01 = __builtin_amdgcn_mfma_f32_16x16x32_bf16(ha0, gb1, zz, 0, 0, 0);
    const f32x4 s11 = __builtin_amdgcn_mfma_f32_16x16x32_bf16(ha1, gb1, zz, 0, 0, 0);

    f32x4 p00, p10, p01, p11;
#pragma unroll
    for (int r = 0; r < 4; ++r) {
      p00[r] = exp2f(s00[r]) * Linv0;
      p10[r] = exp2f(s10[r]) * Linv0;
      p01[r] = exp2f(s01[r]) * Linv1;
      p11[r] = exp2f(s11[r]) * Linv1;
    }

    // scatter p into this wave's swizzled LDS tile (16B units)
    *(f32x4*)&plds[w][lm]     [((lh    ) ^ k7) << 2] = p00;
    *(f32x4*)&plds[w][lm]     [((lh + 4) ^ k7) << 2] = p10;
    *(f32x4*)&plds[w][16 + lm][((lh    ) ^ k7) << 2] = p01;
    *(f32x4*)&plds[w][16 + lm][((lh + 4) ^ k7) << 2] = p11;

    // alpha NT stores: each instr writes 8 rows x full 128B line
#pragma unroll
    for (int j = 0; j < 4; ++j) {
      const int row = j * 8 + nrow;
      const f32x4 pv = *(const f32x4*)&plds[w][row][(uu ^ (row & 7)) << 2];
      __builtin_nontemporal_store(pv, (f32x4*)(aB + (size_t)row * NN + m0 + uu * 4));
    }

    // A-frags for r-GEMM: p[n=lm(+16)][m = lh*8 .. +7] from swizzled tile
    const f32x4 q00 = *(const f32x4*)&plds[w][lm]     [((2 * lh    ) ^ k7) << 2];
    const f32x4 q01 = *(const f32x4*)&plds[w][lm]     [((2 * lh + 1) ^ k7) << 2];
    const f32x4 q10 = *(const f32x4*)&plds[w][16 + lm][((2 * lh    ) ^ k7) << 2];
    const f32x4 q11 = *(const f32x4*)&plds[w][16 + lm][((2 * lh + 1) ^ k7) << 2];
    const bf16x8 pa0 = pack8(q00, q01);
    const bf16x8 pa1 = pack8(q10, q11);

#pragma unroll
    for (int ci = 0; ci < 4; ++ci) {
      const bf16x8 xv = *(const bf16x8*)(xB + (size_t)(ci * 16 + lm) * NN + m0 + lh * 8);
      racc[0][ci] = __builtin_amdgcn_mfma_f32_16x16x32_bf16(pa0, xv, racc[0][ci], 0, 0, 0);
      racc[1][ci] = __builtin_amdgcn_mfma_f32_16x16x32_bf16(pa1, xv, racc[1][ci], 0, 0, 0);
    }
    ha0 = na0; ha1 = na1;
  }

  // ---- Phase 3: reduce partial r across waves ---------------------------
#pragma unroll
  for (int gi = 0; gi < 2; ++gi)
#pragma unroll
    for (int ci = 0; ci < 4; ++ci)
#pragma unroll
      for (int r = 0; r < 4; ++r)
        atomicAdd(&rtile[gi * 16 + lh * 4 + r][ci * 16 + lm], racc[gi][ci][r]);
  __syncthreads();

  // epilogue: out[b][c][n] = relu(r + x), coalesced NT float4
  const int c  = tid >> 3;
  const int j4 = (tid & 7) << 2;
  f32x4 v;
#pragma unroll
  for (int k = 0; k < 4; ++k) v[k] = rtile[j4 + k][c];
  const size_t oo = ((size_t)b * NC + c) * NN + n0 + j4;
  const f32x4 xr = *(const f32x4*)(x + oo);
#pragma unroll
  for (int k = 0; k < 4; ++k) {
    const float t = v[k] + xr[k];
    v[k] = t > 0.f ? t : 0.f;
  }
  __builtin_nontemporal_store(v, (f32x4*)(outp + oo));
}

// ---------------------------------------------------------------------------
extern "C" void kernel_launch(void* const* d_in, const int* in_sizes, int n_in,
                              void* d_out, int out_size, void* d_ws, size_t ws_size,
                              hipStream_t stream) {
  const float* x  = (const float*)d_in[0];
  const float* Wg = (const float*)d_in[1];
  const float* bg = (const float*)d_in[2];
  const float* Wh = (const float*)d_in[3];
  const float* bh = (const float*)d_in[4];

  float* outp  = (float*)d_out;
  float* alpha = outp + (size_t)NB * NC * NN;   // outputs: relu(r) then alpha

  // workspace: gT (2MB) | hqT (2MB) | xfb (4MB)
  ushort* gT  = (ushort*)d_ws;
  ushort* hqT = gT + (size_t)NB * NN * NA;
  ushort* xfb = hqT + (size_t)NB * NN * NA;

  prep_kernel<<<NB * NN / 256, 256, 0, stream>>>(x, Wg, bg, Wh, bh, gT, hqT, xfb);
  attn_kernel<<<NB * (NN / 32), 512, 0, stream>>>(gT, hqT, xfb, x, outp, alpha);
}